// Round 8
// baseline (421.931 us; speedup 1.0000x reference)
//
#include <hip/hip_runtime.h>

// Problem constants
#define D_    1024
#define HH    16
#define DHEAD 64
#define DFF_  4096
#define NTOK  4096   // B*S = 4*1024
#define SQLEN 1024

typedef unsigned short ushort_t;
typedef __attribute__((ext_vector_type(8))) short short8;
typedef __attribute__((ext_vector_type(4))) float floatx4;

#define LOG2E 1.44269504f

__device__ __forceinline__ unsigned short f2bf(float f) {
  union { float f; unsigned u; } x; x.f = f;
  unsigned r = x.u + 0x7fffu + ((x.u >> 16) & 1u);   // RNE
  return (unsigned short)(r >> 16);
}
__device__ __forceinline__ float bf2f(unsigned short u) {
  union { unsigned u; float f; } x; x.u = ((unsigned)u) << 16;
  return x.f;
}
// pack two fp32 -> bf16 pair in 3 ops (round-half-up + v_perm)
__device__ __forceinline__ unsigned pack2bf_fast(float a, float b) {
  union { float f; unsigned u; } x, y; x.f = a; y.f = b;
  return __builtin_amdgcn_perm(y.u + 0x8000u, x.u + 0x8000u, 0x07060302u);
}
__device__ __forceinline__ float fast_exp2(float x) {
  return __builtin_amdgcn_exp2f(x);
}
// gelu(u) = u - u * rcp(exp2(u*(c1 + c2*u^2)) + 1)
__device__ __forceinline__ float fast_gelu(float u) {
  float u2 = u * u;
  float arg = u * (2.30220414f + 0.10294307f * u2);
  float e = __builtin_amdgcn_exp2f(arg);
  float r = __builtin_amdgcn_rcpf(e + 1.0f);
  return u - u * r;
}

__device__ __forceinline__ void async_ld16(const void* g, void* l) {
  __builtin_amdgcn_global_load_lds(
      (const __attribute__((address_space(1))) unsigned int*)g,
      (__attribute__((address_space(3))) unsigned int*)l, 16, 0, 0);
}

// ---------------- prep: cast x + all 6 weight transposes, one launch ----------------
__global__ __launch_bounds__(256) void prep_kernel(
    const float* __restrict__ x, const float* __restrict__ Wq,
    const float* __restrict__ Wk, const float* __restrict__ Wv,
    const float* __restrict__ Wo, const float* __restrict__ W1,
    const float* __restrict__ W2,
    ushort_t* __restrict__ xb, ushort_t* __restrict__ wqkvt,
    ushort_t* __restrict__ wot, ushort_t* __restrict__ w1t,
    ushort_t* __restrict__ w2t) {
  int bid = blockIdx.x, tid = threadIdx.x;
  if (bid < 4096) {
    int i = bid * 256 + tid;
    float4 v = ((const float4*)x)[i];
    ushort4 o;
    o.x = f2bf(v.x); o.y = f2bf(v.y); o.z = f2bf(v.z); o.w = f2bf(v.w);
    ((ushort4*)xb)[i] = o;
    return;
  }
  __shared__ float tile[32][33];
  const float* W; ushort_t* T; int K, N, n0, k0;
  if (bid < 8192) {
    int id = bid - 4096, z = id >> 10, xy = id & 1023;
    W = (z == 0) ? Wq : (z == 1) ? Wk : (z == 2) ? Wv : Wo;
    T = (z < 3) ? wqkvt + (size_t)z * D_ * D_ : wot;
    K = D_; N = D_;
    n0 = (xy & 31) * 32; k0 = (xy >> 5) * 32;
  } else if (bid < 12288) {
    int id = bid - 8192;
    W = W1; T = w1t; K = D_; N = DFF_;
    n0 = (id & 127) * 32; k0 = (id >> 7) * 32;
  } else {
    int id = bid - 12288;
    W = W2; T = w2t; K = DFF_; N = D_;
    n0 = (id & 31) * 32; k0 = (id >> 5) * 32;
  }
  int tx = tid & 31, ty = tid >> 5;
#pragma unroll
  for (int i = 0; i < 4; i++)
    tile[ty + i * 8][tx] = W[(size_t)(k0 + ty + i * 8) * N + n0 + tx];
  __syncthreads();
#pragma unroll
  for (int i = 0; i < 4; i++)
    T[(size_t)(n0 + ty + i * 8) * K + k0 + tx] = f2bf(tile[tx][ty + i * 8]);
}

// ---------------- bf16 MFMA GEMM, 128x128 tile, BK=64 ----------------
// A staged via global_load_lds (2-panel LDS, 16 KB). B (weights) loaded DIRECTLY
// into MFMA operand registers as global_load_dwordx4 (B^T rows are k-contiguous),
// issued before the barriers so L2 latency hides under the A-staging drain.
// MODE 0: QKV. q,k -> [B][H][S][DH] bf16 (q scaled 0.125*log2e); v -> [B][H][DH][S]
// MODE 2: gelu(c + bias0[n]) -> bf16 o0[m][n]
// MODE 3: bf16 partial: o0[sp*M*N + m*N + n] = bf16(c)   (reduced in ln_red)
template <int MODE>
__global__ __launch_bounds__(256) void gemm_bf16(
    const ushort_t* __restrict__ A, const ushort_t* __restrict__ Bt,
    int M, int N, int K, int Ks, int nb,
    const float* __restrict__ bias0, const float* __restrict__ bias1,
    const float* __restrict__ bias2,
    ushort_t* __restrict__ o0, ushort_t* __restrict__ o1, ushort_t* __restrict__ o2) {
  __shared__ alignas(16) ushort_t sA[2][128 * 32];   // panel = k half (32 each)
  int tid = threadIdx.x;
  int w = tid >> 6, lane = tid & 63, quad = lane >> 4, l16 = lane & 15;
  int wm = w >> 1, wn = w & 1;

  int sp = blockIdx.x / nb;
  int bid = blockIdx.x - sp * nb;
  int gridN = N >> 7;
  int Tn = nb >> 3;                     // tiles per XCD
  int lin = (bid & 7) * Tn + (bid >> 3);
  int ng = gridN << 3;                  // tiles per 8-row group
  int gidx = lin / ng;
  int rem = lin - gidx * ng;
  int m0 = ((gidx << 3) + (rem & 7)) << 7;
  int n0 = (rem >> 3) << 7;
  int kbeg = sp * Ks, kend = kbeg + Ks;

  floatx4 acc[4][4];
#pragma unroll
  for (int i = 0; i < 4; i++)
#pragma unroll
    for (int j = 0; j < 4; j++) acc[i][j] = (floatx4){0.f, 0.f, 0.f, 0.f};

  int srow = lane >> 2, scol = (lane & 3) * 8;
  const ushort_t* gA = A + (size_t)(m0 + w * 16 + srow) * K + scol;
  ushort_t* lA = sA[0] + w * 16 * 32;
  // B row pointer: wave covers rows n0+wn*64+nt*16+l16
  const ushort_t* bp = Bt + (size_t)(n0 + wn * 64 + l16) * K + quad * 8;

  for (int k0 = kbeg; k0 < kend; k0 += 64) {
    // B fragments -> registers (independent of LDS/barriers; issue early)
    short8 br[2][4];
#pragma unroll
    for (int nt = 0; nt < 4; nt++)
#pragma unroll
      for (int kc = 0; kc < 2; kc++)
        br[kc][nt] = *(const short8*)(bp + (size_t)nt * 16 * K + k0 + kc * 32);
    __syncthreads();
#pragma unroll
    for (int h = 0; h < 2; h++)
#pragma unroll
      for (int p = 0; p < 2; p++)
        async_ld16(gA + (size_t)h * 64 * K + k0 + p * 32, lA + p * 4096 + h * 2048);
    __syncthreads();
#pragma unroll
    for (int kc = 0; kc < 2; kc++) {
      short8 af[4];
#pragma unroll
      for (int mt = 0; mt < 4; mt++)
        af[mt] = *(const short8*)(sA[kc] + (wm * 64 + mt * 16 + l16) * 32 + quad * 8);
#pragma unroll
      for (int mt = 0; mt < 4; mt++)
#pragma unroll
        for (int nt = 0; nt < 4; nt++)
          acc[mt][nt] = __builtin_amdgcn_mfma_f32_16x16x32_bf16(af[mt], br[kc][nt],
                                                                acc[mt][nt], 0, 0, 0);
    }
  }

  if (MODE == 0) {
#pragma unroll
    for (int nt = 0; nt < 4; nt++) {
      int cg = n0 + wn * 64 + nt * 16 + l16;
      int sel = cg >> 10, nn = cg & 1023;
      const float* bpp = (sel == 0) ? bias0 : ((sel == 1) ? bias1 : bias2);
      float bb = bpp[nn];
      int hh = nn >> 6, dd = nn & 63;
#pragma unroll
      for (int mt = 0; mt < 4; mt++) {
        int rg0 = m0 + wm * 64 + mt * 16 + quad * 4;
        int b0 = rg0 >> 10, s0 = rg0 & 1023;
        if (sel == 2) {
          ushort4 ov;
          ov.x = f2bf(acc[mt][nt][0] + bb);
          ov.y = f2bf(acc[mt][nt][1] + bb);
          ov.z = f2bf(acc[mt][nt][2] + bb);
          ov.w = f2bf(acc[mt][nt][3] + bb);
          *(ushort4*)(o2 + ((size_t)(b0 * HH + hh) * DHEAD + dd) * SQLEN + s0) = ov;
        } else {
          ushort_t* dst = sel ? o1 : o0;
          float sc = (sel == 0) ? (0.125f * LOG2E) : 1.0f;
#pragma unroll
          for (int r = 0; r < 4; r++)
            dst[((size_t)(b0 * HH + hh) * SQLEN + s0 + r) * DHEAD + dd] =
                f2bf((acc[mt][nt][r] + bb) * sc);
        }
      }
    }
  } else {
    // hoisted addressing: one row base, pointer walk
    size_t rowbase = (size_t)(m0 + wm * 64 + quad * 4) * N + (n0 + wn * 64 + l16);
    if (MODE == 3) rowbase += (size_t)sp * M * N;
    float bb0 = (MODE == 2) ? bias0[(n0 + wn * 64 + l16) & (N - 1)] : 0.f;
    float bb1 = (MODE == 2) ? bias0[(n0 + wn * 64 + 16 + l16) & (N - 1)] : 0.f;
    float bb2 = (MODE == 2) ? bias0[(n0 + wn * 64 + 32 + l16) & (N - 1)] : 0.f;
    float bb3 = (MODE == 2) ? bias0[(n0 + wn * 64 + 48 + l16) & (N - 1)] : 0.f;
#pragma unroll
    for (int mt = 0; mt < 4; mt++) {
#pragma unroll
      for (int r = 0; r < 4; r++) {
        ushort_t* pr = o0 + rowbase + (size_t)(mt * 16 + r) * N;
        if (MODE == 2) {
          pr[0]  = f2bf(fast_gelu(acc[mt][0][r] + bb0));
          pr[16] = f2bf(fast_gelu(acc[mt][1][r] + bb1));
          pr[32] = f2bf(fast_gelu(acc[mt][2][r] + bb2));
          pr[48] = f2bf(fast_gelu(acc[mt][3][r] + bb3));
        } else {
          pr[0]  = f2bf(acc[mt][0][r]);
          pr[16] = f2bf(acc[mt][1][r]);
          pr[32] = f2bf(acc[mt][2][r]);
          pr[48] = f2bf(acc[mt][3][r]);
        }
      }
    }
  }
}

// ---------------- flash attention (S^T form, 128-row q tiles) ----------------
// q,k: [B][H][S][DH] bf16 (q pre-scaled 0.125*log2e). vt: [B][H][DH][S] bf16.
// Block = (bh, 128-row q tile); wave owns 32 q rows (2 groups of 16).
// Fixed-reference exp2 softmax (no running max; scores tiny vs fp32 range).
__global__ __launch_bounds__(256) void flash_attn_kernel(const ushort_t* __restrict__ q,
                                                         const ushort_t* __restrict__ k,
                                                         const ushort_t* __restrict__ vt,
                                                         ushort_t* __restrict__ ctx) {
  __shared__ alignas(16) ushort_t sQ[2][128 * 32];    // 16 KB
  __shared__ alignas(16) ushort_t sK[2][64 * 32];     // 8 KB
  __shared__ alignas(16) ushort_t sVt[2][64 * 32];    // 8 KB
  __shared__ alignas(16) char sP[4][2][2][16 * 80];   // [wave][g][kc], 80B row stride
  int tid = threadIdx.x;
  int w = tid >> 6, lane = tid & 63, quad = lane >> 4, l16 = lane & 15;
  int bh = blockIdx.x, qt = blockIdx.y;
  int b_ = bh >> 4, h_ = bh & 15;

  const ushort_t* Qp = q + ((size_t)bh * SQLEN + qt * 128) * DHEAD;
  const ushort_t* Kp = k + (size_t)bh * SQLEN * DHEAD;
  const ushort_t* Vtp = vt + (size_t)bh * DHEAD * SQLEN;

  int srow = lane >> 2, scol8 = (lane & 3) * 8;

  // stage Q once: 128 rows x 64 cols -> 2 panels of [128][32]
#pragma unroll
  for (int h = 0; h < 2; h++)
#pragma unroll
    for (int p = 0; p < 2; p++)
      async_ld16(Qp + (h * 64 + w * 16 + srow) * 64 + p * 32 + scol8,
                 (char*)sQ + p * 8192 + (h * 64 + w * 16) * 64);

  float l_run[2] = {0.f, 0.f};
  floatx4 o_acc[2][4];
#pragma unroll
  for (int g = 0; g < 2; g++)
#pragma unroll
    for (int dt = 0; dt < 4; dt++) o_acc[g][dt] = (floatx4){0.f, 0.f, 0.f, 0.f};

  for (int kt = 0; kt < 16; kt++) {
    __syncthreads();
#pragma unroll
    for (int t = 0; t < 2; t++) {
      int id = w * 2 + t, panel = id & 1, rg = id >> 1;
      int row = rg * 16 + srow, col = panel * 32 + scol8;
      async_ld16(Kp + kt * 64 * 64 + row * 64 + col,
                 (char*)sK + panel * 4096 + rg * 1024);
      async_ld16(Vtp + (size_t)row * SQLEN + kt * 64 + col,
                 (char*)sVt + panel * 4096 + rg * 1024);
    }
    __syncthreads();

    // S^T = K Q^T for both q-groups (share kf loads)
    floatx4 st[2][4];
#pragma unroll
    for (int g = 0; g < 2; g++)
#pragma unroll
      for (int nt = 0; nt < 4; nt++) st[g][nt] = (floatx4){0.f, 0.f, 0.f, 0.f};
#pragma unroll
    for (int kc = 0; kc < 2; kc++) {
      short8 aq0 = *(const short8*)(sQ[kc] + (w * 32 + l16) * 32 + quad * 8);
      short8 aq1 = *(const short8*)(sQ[kc] + (w * 32 + 16 + l16) * 32 + quad * 8);
#pragma unroll
      for (int nt = 0; nt < 4; nt++) {
        short8 kf = *(const short8*)(sK[kc] + (nt * 16 + l16) * 32 + quad * 8);
        st[0][nt] = __builtin_amdgcn_mfma_f32_16x16x32_bf16(kf, aq0, st[0][nt], 0, 0, 0);
        st[1][nt] = __builtin_amdgcn_mfma_f32_16x16x32_bf16(kf, aq1, st[1][nt], 0, 0, 0);
      }
    }

    // p = exp2(score); per-lane l accumulate; pack + write P (B-operand layout)
#pragma unroll
    for (int g = 0; g < 2; g++) {
#pragma unroll
      for (int nt = 0; nt < 4; nt++) {
        float p0 = fast_exp2(st[g][nt][0]);
        float p1 = fast_exp2(st[g][nt][1]);
        float p2 = fast_exp2(st[g][nt][2]);
        float p3 = fast_exp2(st[g][nt][3]);
        l_run[g] += (p0 + p1) + (p2 + p3);
        uint2 d2;
        d2.x = pack2bf_fast(p0, p1);
        d2.y = pack2bf_fast(p2, p3);
        *(uint2*)(&sP[w][g][nt >> 1][0] + l16 * 80 + (nt & 1) * 32 + quad * 8) = d2;
      }
    }

    // O^T += V^T P^T (share vf loads across groups)
#pragma unroll
    for (int kc = 0; kc < 2; kc++) {
      short8 pf0 = *(const short8*)(&sP[w][0][kc][0] + l16 * 80 + quad * 16);
      short8 pf1 = *(const short8*)(&sP[w][1][kc][0] + l16 * 80 + quad * 16);
#pragma unroll
      for (int dt = 0; dt < 4; dt++) {
        short8 vf = *(const short8*)(sVt[kc] + (dt * 16 + l16) * 32 + quad * 8);
        o_acc[0][dt] = __builtin_amdgcn_mfma_f32_16x16x32_bf16(vf, pf0, o_acc[0][dt], 0, 0, 0);
        o_acc[1][dt] = __builtin_amdgcn_mfma_f32_16x16x32_bf16(vf, pf1, o_acc[1][dt], 0, 0, 0);
      }
    }
  }

#pragma unroll
  for (int g = 0; g < 2; g++) {
    float l = l_run[g];
    l += __shfl_xor(l, 16);
    l += __shfl_xor(l, 32);
    float inv = 1.f / fmaxf(l, 1e-30f);
    int s_ = qt * 128 + w * 32 + g * 16 + l16;
    ushort_t* cp = ctx + (size_t)(b_ * SQLEN + s_) * D_ + h_ * DHEAD + quad * 4;
#pragma unroll
    for (int dt = 0; dt < 4; dt++) {
      ushort4 ov;
      ov.x = f2bf(o_acc[g][dt][0] * inv);
      ov.y = f2bf(o_acc[g][dt][1] * inv);
      ov.z = f2bf(o_acc[g][dt][2] * inv);
      ov.w = f2bf(o_acc[g][dt][3] * inv);
      *(ushort4*)(cp + dt * 16) = ov;
    }
  }
}

// ---------------- LayerNorm with split-K partial reduction ----------------
template <int S, int WB>
__global__ __launch_bounds__(256) void ln_red_kernel(
    const ushort_t* __restrict__ parts, const float* __restrict__ bias,
    const float* __restrict__ res, const float* __restrict__ g,
    const float* __restrict__ b, float* __restrict__ outf,
    ushort_t* __restrict__ outb) {
  int row = blockIdx.x, tid = threadIdx.x;
  float4 v = ((const float4*)(res + (size_t)row * D_))[tid];
  float4 bb = ((const float4*)bias)[tid];
  v.x += bb.x; v.y += bb.y; v.z += bb.z; v.w += bb.w;
#pragma unroll
  for (int s = 0; s < S; s++) {
    ushort4 p = ((const ushort4*)(parts + (size_t)s * NTOK * D_ + (size_t)row * D_))[tid];
    v.x += bf2f(p.x); v.y += bf2f(p.y); v.z += bf2f(p.z); v.w += bf2f(p.w);
  }
  float s1 = v.x + v.y + v.z + v.w;
  float s2 = v.x * v.x + v.y * v.y + v.z * v.z + v.w * v.w;
#pragma unroll
  for (int off = 32; off > 0; off >>= 1) {
    s1 += __shfl_down(s1, off);
    s2 += __shfl_down(s2, off);
  }
  __shared__ float red[10];
  int wid = tid >> 6, lane = tid & 63;
  if (lane == 0) { red[wid] = s1; red[4 + wid] = s2; }
  __syncthreads();
  if (tid == 0) {
    float ts = red[0] + red[1] + red[2] + red[3];
    float ts2 = red[4] + red[5] + red[6] + red[7];
    float mu = ts * (1.f / 1024.f);
    float var = ts2 * (1.f / 1024.f) - mu * mu;
    red[8] = mu;
    red[9] = rsqrtf(var + 1e-5f);
  }
  __syncthreads();
  float mu = red[8], rsg = red[9];
  float4 gv = ((const float4*)g)[tid];
  float4 bv = ((const float4*)b)[tid];
  float4 o;
  o.x = (v.x - mu) * rsg * gv.x + bv.x;
  o.y = (v.y - mu) * rsg * gv.y + bv.y;
  o.z = (v.z - mu) * rsg * gv.z + bv.z;
  o.w = (v.w - mu) * rsg * gv.w + bv.w;
  if (outf) ((float4*)(outf + (size_t)row * D_))[tid] = o;
  if (WB) {
    ushort4 ob;
    ob.x = f2bf(o.x); ob.y = f2bf(o.y); ob.z = f2bf(o.z); ob.w = f2bf(o.w);
    ((ushort4*)(outb + (size_t)row * D_))[tid] = ob;
  }
}

extern "C" void kernel_launch(void* const* d_in, const int* in_sizes, int n_in,
                              void* d_out, int out_size, void* d_ws, size_t ws_size,
                              hipStream_t stream) {
  const float* x   = (const float*)d_in[0];
  const float* Wq  = (const float*)d_in[1];
  const float* bq  = (const float*)d_in[2];
  const float* Wk  = (const float*)d_in[3];
  const float* bk  = (const float*)d_in[4];
  const float* Wv  = (const float*)d_in[5];
  const float* bv  = (const float*)d_in[6];
  const float* Wo  = (const float*)d_in[7];
  const float* bo  = (const float*)d_in[8];
  const float* g1  = (const float*)d_in[9];
  const float* b1  = (const float*)d_in[10];
  const float* W1  = (const float*)d_in[11];
  const float* bm1 = (const float*)d_in[12];
  const float* W2  = (const float*)d_in[13];
  const float* bm2 = (const float*)d_in[14];
  const float* g2  = (const float*)d_in[15];
  const float* b2  = (const float*)d_in[16];
  float* out = (float*)d_out;

  char* ws = (char*)d_ws;
  const size_t MB = 1024 * 1024;
  ushort_t* xb    = (ushort_t*)(ws + 0);         // 8 MB   (dead after QKV gemm)
  ushort_t* wqkvt = (ushort_t*)(ws + 8 * MB);    // 6 MB
  ushort_t* wot   = (ushort_t*)(ws + 14 * MB);   // 2 MB
  ushort_t* w1t   = (ushort_t*)(ws + 16 * MB);   // 8 MB
  ushort_t* w2t   = (ushort_t*)(ws + 24 * MB);   // 8 MB
  ushort_t* qb    = (ushort_t*)(ws + 32 * MB);   // 8 MB   (dead after flash)
  ushort_t* kb    = (ushort_t*)(ws + 40 * MB);   // 8 MB   (dead after flash)
  ushort_t* vtb   = (ushort_t*)(ws + 48 * MB);   // 8 MB   (dead after flash)
  ushort_t* ctx   = (ushort_t*)(ws + 56 * MB);   // 8 MB   (dead after Wo gemm)
  float*    x1    = (float*)   (ws + 64 * MB);   // 16 MB
  ushort_t* x1b   = (ushort_t*)(ws + 80 * MB);   // 8 MB
  ushort_t* hbuf  = (ushort_t*)(ws + 88 * MB);   // 32 MB
  ushort_t* pWo   = (ushort_t*)(ws + 32 * MB);   // 16 MB over qb+kb
  ushort_t* pMd   = (ushort_t*)(ws + 32 * MB);   // 32 MB over qb..ctx
  (void)ws_size; (void)in_sizes; (void)n_in; (void)out_size;

  // 1. fused prep: cast x + all weight transposes
  hipLaunchKernelGGL(prep_kernel, dim3(16384), dim3(256), 0, stream,
                     x, Wq, Wk, Wv, Wo, W1, W2, xb, wqkvt, wot, w1t, w2t);

  // 2. fused QKV projection (M=4096, N=3072, K=1024); V written transposed
  hipLaunchKernelGGL((gemm_bf16<0>), dim3(768), dim3(256), 0, stream,
                     xb, wqkvt, NTOK, 3072, D_, D_, 768, bq, bk, bv, qb, kb, vtb);

  // 3. attention (128-row q tiles)
  hipLaunchKernelGGL(flash_attn_kernel, dim3(4 * HH, SQLEN / 128), dim3(256), 0, stream,
                     qb, kb, vtb, ctx);

  // 4. output projection, split-K=2 -> bf16 partials pWo
  hipLaunchKernelGGL((gemm_bf16<3>), dim3(512), dim3(256), 0, stream,
                     ctx, wot, NTOK, D_, D_, 512, 256,
                     (const float*)nullptr, (const float*)nullptr,
                     (const float*)nullptr, pWo, (ushort_t*)nullptr, (ushort_t*)nullptr);

  // 5. LN1 = LN(x + bo + sum partials) -> x1 (fp32) + x1b (bf16)
  hipLaunchKernelGGL((ln_red_kernel<2, 1>), dim3(NTOK), dim3(256), 0, stream,
                     pWo, bo, x, g1, b1, x1, x1b);

  // 6. MLP up + GELU -> hbuf (M=4096, N=4096, K=1024)
  hipLaunchKernelGGL((gemm_bf16<2>), dim3(1024), dim3(256), 0, stream,
                     x1b, w1t, NTOK, DFF_, D_, D_, 1024, bm1, (const float*)nullptr,
                     (const float*)nullptr, hbuf, (ushort_t*)nullptr, (ushort_t*)nullptr);

  // 7. MLP down, split-K=4 -> bf16 partials pMd
  hipLaunchKernelGGL((gemm_bf16<3>), dim3(1024), dim3(256), 0, stream,
                     hbuf, w2t, NTOK, D_, DFF_, 1024, 256,
                     (const float*)nullptr, (const float*)nullptr,
                     (const float*)nullptr, pMd, (ushort_t*)nullptr, (ushort_t*)nullptr);

  // 8. LN2 = LN(x1 + bm2 + sum partials) -> out
  hipLaunchKernelGGL((ln_red_kernel<4, 0>), dim3(NTOK), dim3(256), 0, stream,
                     pMd, bm2, x1, g2, b2, out, (ushort_t*)nullptr);
}

// Round 9
// 336.049 us; speedup vs baseline: 1.2556x; 1.2556x over previous
//
#include <hip/hip_runtime.h>

// Problem constants
#define D_    1024
#define HH    16
#define DHEAD 64
#define DFF_  4096
#define NTOK  4096   // B*S = 4*1024
#define SQLEN 1024

typedef unsigned short ushort_t;
typedef __attribute__((ext_vector_type(8))) short short8;
typedef __attribute__((ext_vector_type(4))) float floatx4;

#define LOG2E 1.44269504f

__device__ __forceinline__ unsigned short f2bf(float f) {
  union { float f; unsigned u; } x; x.f = f;
  unsigned r = x.u + 0x7fffu + ((x.u >> 16) & 1u);   // RNE
  return (unsigned short)(r >> 16);
}
__device__ __forceinline__ float bf2f(unsigned short u) {
  union { unsigned u; float f; } x; x.u = ((unsigned)u) << 16;
  return x.f;
}
// pack two fp32 -> bf16 pair in 3 ops (round-half-up + v_perm)
__device__ __forceinline__ unsigned pack2bf_fast(float a, float b) {
  union { float f; unsigned u; } x, y; x.f = a; y.f = b;
  return __builtin_amdgcn_perm(y.u + 0x8000u, x.u + 0x8000u, 0x07060302u);
}
__device__ __forceinline__ float fast_exp2(float x) {
  return __builtin_amdgcn_exp2f(x);
}
// gelu(u) = u - u * rcp(exp2(u*(c1 + c2*u^2)) + 1)
__device__ __forceinline__ float fast_gelu(float u) {
  float u2 = u * u;
  float arg = u * (2.30220414f + 0.10294307f * u2);
  float e = __builtin_amdgcn_exp2f(arg);
  float r = __builtin_amdgcn_rcpf(e + 1.0f);
  return u - u * r;
}

__device__ __forceinline__ void async_ld16(const void* g, void* l) {
  __builtin_amdgcn_global_load_lds(
      (const __attribute__((address_space(1))) unsigned int*)g,
      (__attribute__((address_space(3))) unsigned int*)l, 16, 0, 0);
}

// ---------------- prep: cast x + all 6 weight transposes, one launch ----------------
__global__ __launch_bounds__(256) void prep_kernel(
    const float* __restrict__ x, const float* __restrict__ Wq,
    const float* __restrict__ Wk, const float* __restrict__ Wv,
    const float* __restrict__ Wo, const float* __restrict__ W1,
    const float* __restrict__ W2,
    ushort_t* __restrict__ xb, ushort_t* __restrict__ wqkvt,
    ushort_t* __restrict__ wot, ushort_t* __restrict__ w1t,
    ushort_t* __restrict__ w2t) {
  int bid = blockIdx.x, tid = threadIdx.x;
  if (bid < 4096) {
    int i = bid * 256 + tid;
    float4 v = ((const float4*)x)[i];
    ushort4 o;
    o.x = f2bf(v.x); o.y = f2bf(v.y); o.z = f2bf(v.z); o.w = f2bf(v.w);
    ((ushort4*)xb)[i] = o;
    return;
  }
  __shared__ float tile[32][33];
  const float* W; ushort_t* T; int K, N, n0, k0;
  if (bid < 8192) {
    int id = bid - 4096, z = id >> 10, xy = id & 1023;
    W = (z == 0) ? Wq : (z == 1) ? Wk : (z == 2) ? Wv : Wo;
    T = (z < 3) ? wqkvt + (size_t)z * D_ * D_ : wot;
    K = D_; N = D_;
    n0 = (xy & 31) * 32; k0 = (xy >> 5) * 32;
  } else if (bid < 12288) {
    int id = bid - 8192;
    W = W1; T = w1t; K = D_; N = DFF_;
    n0 = (id & 127) * 32; k0 = (id >> 7) * 32;
  } else {
    int id = bid - 12288;
    W = W2; T = w2t; K = DFF_; N = D_;
    n0 = (id & 31) * 32; k0 = (id >> 5) * 32;
  }
  int tx = tid & 31, ty = tid >> 5;
#pragma unroll
  for (int i = 0; i < 4; i++)
    tile[ty + i * 8][tx] = W[(size_t)(k0 + ty + i * 8) * N + n0 + tx];
  __syncthreads();
#pragma unroll
  for (int i = 0; i < 4; i++)
    T[(size_t)(n0 + ty + i * 8) * K + k0 + tx] = f2bf(tile[tx][ty + i * 8]);
}

// ---------------- bf16 MFMA GEMM, 128x128 tile, BK=64 (2-panel LDS) ----------------
// Both A and B staged via global_load_lds (round-7 proven structure; round-8's
// B-direct-to-register regressed: br loads drained serially at the barrier).
// MODE 0: QKV. q,k -> [B][H][S][DH] bf16 (q scaled 0.125*log2e); v -> [B][H][DH][S]
// MODE 2: gelu(c + bias0[n]) -> bf16 o0[m][n]
// MODE 3: bf16 partial: o0[sp*M*N + m*N + n] = bf16(c)   (reduced in ln_red)
template <int MODE>
__global__ __launch_bounds__(256) void gemm_bf16(
    const ushort_t* __restrict__ A, const ushort_t* __restrict__ Bt,
    int M, int N, int K, int Ks, int nb,
    const float* __restrict__ bias0, const float* __restrict__ bias1,
    const float* __restrict__ bias2,
    ushort_t* __restrict__ o0, ushort_t* __restrict__ o1, ushort_t* __restrict__ o2) {
  __shared__ alignas(16) ushort_t sA[2][128 * 32];   // panel = k half (32 each)
  __shared__ alignas(16) ushort_t sB[2][128 * 32];
  int tid = threadIdx.x;
  int w = tid >> 6, lane = tid & 63, quad = lane >> 4, l16 = lane & 15;
  int wm = w >> 1, wn = w & 1;

  int sp = blockIdx.x / nb;
  int bid = blockIdx.x - sp * nb;
  int gridN = N >> 7;
  int Tn = nb >> 3;                     // tiles per XCD
  int lin = (bid & 7) * Tn + (bid >> 3);
  int ng = gridN << 3;                  // tiles per 8-row group
  int gidx = lin / ng;
  int rem = lin - gidx * ng;
  int m0 = ((gidx << 3) + (rem & 7)) << 7;
  int n0 = (rem >> 3) << 7;
  int kbeg = sp * Ks, kend = kbeg + Ks;

  floatx4 acc[4][4];
#pragma unroll
  for (int i = 0; i < 4; i++)
#pragma unroll
    for (int j = 0; j < 4; j++) acc[i][j] = (floatx4){0.f, 0.f, 0.f, 0.f};

  int srow = lane >> 2, scol = (lane & 3) * 8;
  const ushort_t* gA = A + (size_t)(m0 + w * 16 + srow) * K + scol;
  const ushort_t* gB = Bt + (size_t)(n0 + w * 16 + srow) * K + scol;
  ushort_t* lA = sA[0] + w * 16 * 32;
  ushort_t* lB = sB[0] + w * 16 * 32;

  for (int k0 = kbeg; k0 < kend; k0 += 64) {
    __syncthreads();
#pragma unroll
    for (int h = 0; h < 2; h++)
#pragma unroll
      for (int p = 0; p < 2; p++) {
        async_ld16(gA + (size_t)h * 64 * K + k0 + p * 32, lA + p * 4096 + h * 2048);
        async_ld16(gB + (size_t)h * 64 * K + k0 + p * 32, lB + p * 4096 + h * 2048);
      }
    __syncthreads();
#pragma unroll
    for (int kc = 0; kc < 2; kc++) {
      short8 af[4], bfr[4];
#pragma unroll
      for (int mt = 0; mt < 4; mt++)
        af[mt] = *(const short8*)(sA[kc] + (wm * 64 + mt * 16 + l16) * 32 + quad * 8);
#pragma unroll
      for (int nt = 0; nt < 4; nt++)
        bfr[nt] = *(const short8*)(sB[kc] + (wn * 64 + nt * 16 + l16) * 32 + quad * 8);
#pragma unroll
      for (int mt = 0; mt < 4; mt++)
#pragma unroll
        for (int nt = 0; nt < 4; nt++)
          acc[mt][nt] = __builtin_amdgcn_mfma_f32_16x16x32_bf16(af[mt], bfr[nt],
                                                                acc[mt][nt], 0, 0, 0);
    }
  }

  if (MODE == 0) {
#pragma unroll
    for (int nt = 0; nt < 4; nt++) {
      int cg = n0 + wn * 64 + nt * 16 + l16;
      int sel = cg >> 10, nn = cg & 1023;
      const float* bpp = (sel == 0) ? bias0 : ((sel == 1) ? bias1 : bias2);
      float bb = bpp[nn];
      int hh = nn >> 6, dd = nn & 63;
#pragma unroll
      for (int mt = 0; mt < 4; mt++) {
        int rg0 = m0 + wm * 64 + mt * 16 + quad * 4;
        int b0 = rg0 >> 10, s0 = rg0 & 1023;
        if (sel == 2) {
          ushort4 ov;
          ov.x = f2bf(acc[mt][nt][0] + bb);
          ov.y = f2bf(acc[mt][nt][1] + bb);
          ov.z = f2bf(acc[mt][nt][2] + bb);
          ov.w = f2bf(acc[mt][nt][3] + bb);
          *(ushort4*)(o2 + ((size_t)(b0 * HH + hh) * DHEAD + dd) * SQLEN + s0) = ov;
        } else {
          ushort_t* dst = sel ? o1 : o0;
          float sc = (sel == 0) ? (0.125f * LOG2E) : 1.0f;
#pragma unroll
          for (int r = 0; r < 4; r++)
            dst[((size_t)(b0 * HH + hh) * SQLEN + s0 + r) * DHEAD + dd] =
                f2bf((acc[mt][nt][r] + bb) * sc);
        }
      }
    }
  } else {
    // hoisted addressing: one row base, pointer walk
    size_t rowbase = (size_t)(m0 + wm * 64 + quad * 4) * N + (n0 + wn * 64 + l16);
    if (MODE == 3) rowbase += (size_t)sp * M * N;
    float bb0 = (MODE == 2) ? bias0[(n0 + wn * 64 + l16) & (N - 1)] : 0.f;
    float bb1 = (MODE == 2) ? bias0[(n0 + wn * 64 + 16 + l16) & (N - 1)] : 0.f;
    float bb2 = (MODE == 2) ? bias0[(n0 + wn * 64 + 32 + l16) & (N - 1)] : 0.f;
    float bb3 = (MODE == 2) ? bias0[(n0 + wn * 64 + 48 + l16) & (N - 1)] : 0.f;
#pragma unroll
    for (int mt = 0; mt < 4; mt++) {
#pragma unroll
      for (int r = 0; r < 4; r++) {
        ushort_t* pr = o0 + rowbase + (size_t)(mt * 16 + r) * N;
        if (MODE == 2) {
          pr[0]  = f2bf(fast_gelu(acc[mt][0][r] + bb0));
          pr[16] = f2bf(fast_gelu(acc[mt][1][r] + bb1));
          pr[32] = f2bf(fast_gelu(acc[mt][2][r] + bb2));
          pr[48] = f2bf(fast_gelu(acc[mt][3][r] + bb3));
        } else {
          pr[0]  = f2bf(acc[mt][0][r]);
          pr[16] = f2bf(acc[mt][1][r]);
          pr[32] = f2bf(acc[mt][2][r]);
          pr[48] = f2bf(acc[mt][3][r]);
        }
      }
    }
  }
}

// ---------------- flash attention (S^T form, 128-row q tiles) ----------------
// q,k: [B][H][S][DH] bf16 (q pre-scaled 0.125*log2e). vt: [B][H][DH][S] bf16.
// Block = (bh, 128-row q tile); wave owns 32 q rows (2 groups of 16).
// Fixed-reference exp2 softmax (no running max; scores tiny vs fp32 range).
__global__ __launch_bounds__(256) void flash_attn_kernel(const ushort_t* __restrict__ q,
                                                         const ushort_t* __restrict__ k,
                                                         const ushort_t* __restrict__ vt,
                                                         ushort_t* __restrict__ ctx) {
  __shared__ alignas(16) ushort_t sQ[2][128 * 32];    // 16 KB
  __shared__ alignas(16) ushort_t sK[2][64 * 32];     // 8 KB
  __shared__ alignas(16) ushort_t sVt[2][64 * 32];    // 8 KB
  __shared__ alignas(16) char sP[4][2][2][16 * 80];   // [wave][g][kc], 80B row stride
  int tid = threadIdx.x;
  int w = tid >> 6, lane = tid & 63, quad = lane >> 4, l16 = lane & 15;
  int bh = blockIdx.x, qt = blockIdx.y;
  int b_ = bh >> 4, h_ = bh & 15;

  const ushort_t* Qp = q + ((size_t)bh * SQLEN + qt * 128) * DHEAD;
  const ushort_t* Kp = k + (size_t)bh * SQLEN * DHEAD;
  const ushort_t* Vtp = vt + (size_t)bh * DHEAD * SQLEN;

  int srow = lane >> 2, scol8 = (lane & 3) * 8;

  // stage Q once: 128 rows x 64 cols -> 2 panels of [128][32]
#pragma unroll
  for (int h = 0; h < 2; h++)
#pragma unroll
    for (int p = 0; p < 2; p++)
      async_ld16(Qp + (h * 64 + w * 16 + srow) * 64 + p * 32 + scol8,
                 (char*)sQ + p * 8192 + (h * 64 + w * 16) * 64);

  float l_run[2] = {0.f, 0.f};
  floatx4 o_acc[2][4];
#pragma unroll
  for (int g = 0; g < 2; g++)
#pragma unroll
    for (int dt = 0; dt < 4; dt++) o_acc[g][dt] = (floatx4){0.f, 0.f, 0.f, 0.f};

  for (int kt = 0; kt < 16; kt++) {
    __syncthreads();
#pragma unroll
    for (int t = 0; t < 2; t++) {
      int id = w * 2 + t, panel = id & 1, rg = id >> 1;
      int row = rg * 16 + srow, col = panel * 32 + scol8;
      async_ld16(Kp + kt * 64 * 64 + row * 64 + col,
                 (char*)sK + panel * 4096 + rg * 1024);
      async_ld16(Vtp + (size_t)row * SQLEN + kt * 64 + col,
                 (char*)sVt + panel * 4096 + rg * 1024);
    }
    __syncthreads();

    // S^T = K Q^T for both q-groups (share kf loads)
    floatx4 st[2][4];
#pragma unroll
    for (int g = 0; g < 2; g++)
#pragma unroll
      for (int nt = 0; nt < 4; nt++) st[g][nt] = (floatx4){0.f, 0.f, 0.f, 0.f};
#pragma unroll
    for (int kc = 0; kc < 2; kc++) {
      short8 aq0 = *(const short8*)(sQ[kc] + (w * 32 + l16) * 32 + quad * 8);
      short8 aq1 = *(const short8*)(sQ[kc] + (w * 32 + 16 + l16) * 32 + quad * 8);
#pragma unroll
      for (int nt = 0; nt < 4; nt++) {
        short8 kf = *(const short8*)(sK[kc] + (nt * 16 + l16) * 32 + quad * 8);
        st[0][nt] = __builtin_amdgcn_mfma_f32_16x16x32_bf16(kf, aq0, st[0][nt], 0, 0, 0);
        st[1][nt] = __builtin_amdgcn_mfma_f32_16x16x32_bf16(kf, aq1, st[1][nt], 0, 0, 0);
      }
    }

    // p = exp2(score); per-lane l accumulate; pack + write P (B-operand layout)
#pragma unroll
    for (int g = 0; g < 2; g++) {
#pragma unroll
      for (int nt = 0; nt < 4; nt++) {
        float p0 = fast_exp2(st[g][nt][0]);
        float p1 = fast_exp2(st[g][nt][1]);
        float p2 = fast_exp2(st[g][nt][2]);
        float p3 = fast_exp2(st[g][nt][3]);
        l_run[g] += (p0 + p1) + (p2 + p3);
        uint2 d2;
        d2.x = pack2bf_fast(p0, p1);
        d2.y = pack2bf_fast(p2, p3);
        *(uint2*)(&sP[w][g][nt >> 1][0] + l16 * 80 + (nt & 1) * 32 + quad * 8) = d2;
      }
    }

    // O^T += V^T P^T (share vf loads across groups)
#pragma unroll
    for (int kc = 0; kc < 2; kc++) {
      short8 pf0 = *(const short8*)(&sP[w][0][kc][0] + l16 * 80 + quad * 16);
      short8 pf1 = *(const short8*)(&sP[w][1][kc][0] + l16 * 80 + quad * 16);
#pragma unroll
      for (int dt = 0; dt < 4; dt++) {
        short8 vf = *(const short8*)(sVt[kc] + (dt * 16 + l16) * 32 + quad * 8);
        o_acc[0][dt] = __builtin_amdgcn_mfma_f32_16x16x32_bf16(vf, pf0, o_acc[0][dt], 0, 0, 0);
        o_acc[1][dt] = __builtin_amdgcn_mfma_f32_16x16x32_bf16(vf, pf1, o_acc[1][dt], 0, 0, 0);
      }
    }
  }

#pragma unroll
  for (int g = 0; g < 2; g++) {
    float l = l_run[g];
    l += __shfl_xor(l, 16);
    l += __shfl_xor(l, 32);
    float inv = 1.f / fmaxf(l, 1e-30f);
    int s_ = qt * 128 + w * 32 + g * 16 + l16;
    ushort_t* cp = ctx + (size_t)(b_ * SQLEN + s_) * D_ + h_ * DHEAD + quad * 4;
#pragma unroll
    for (int dt = 0; dt < 4; dt++) {
      ushort4 ov;
      ov.x = f2bf(o_acc[g][dt][0] * inv);
      ov.y = f2bf(o_acc[g][dt][1] * inv);
      ov.z = f2bf(o_acc[g][dt][2] * inv);
      ov.w = f2bf(o_acc[g][dt][3] * inv);
      *(ushort4*)(cp + dt * 16) = ov;
    }
  }
}

// ---------------- LayerNorm with split-K partial reduction ----------------
template <int S, int WB>
__global__ __launch_bounds__(256) void ln_red_kernel(
    const ushort_t* __restrict__ parts, const float* __restrict__ bias,
    const float* __restrict__ res, const float* __restrict__ g,
    const float* __restrict__ b, float* __restrict__ outf,
    ushort_t* __restrict__ outb) {
  int row = blockIdx.x, tid = threadIdx.x;
  float4 v = ((const float4*)(res + (size_t)row * D_))[tid];
  float4 bb = ((const float4*)bias)[tid];
  v.x += bb.x; v.y += bb.y; v.z += bb.z; v.w += bb.w;
#pragma unroll
  for (int s = 0; s < S; s++) {
    ushort4 p = ((const ushort4*)(parts + (size_t)s * NTOK * D_ + (size_t)row * D_))[tid];
    v.x += bf2f(p.x); v.y += bf2f(p.y); v.z += bf2f(p.z); v.w += bf2f(p.w);
  }
  float s1 = v.x + v.y + v.z + v.w;
  float s2 = v.x * v.x + v.y * v.y + v.z * v.z + v.w * v.w;
#pragma unroll
  for (int off = 32; off > 0; off >>= 1) {
    s1 += __shfl_down(s1, off);
    s2 += __shfl_down(s2, off);
  }
  __shared__ float red[10];
  int wid = tid >> 6, lane = tid & 63;
  if (lane == 0) { red[wid] = s1; red[4 + wid] = s2; }
  __syncthreads();
  if (tid == 0) {
    float ts = red[0] + red[1] + red[2] + red[3];
    float ts2 = red[4] + red[5] + red[6] + red[7];
    float mu = ts * (1.f / 1024.f);
    float var = ts2 * (1.f / 1024.f) - mu * mu;
    red[8] = mu;
    red[9] = rsqrtf(var + 1e-5f);
  }
  __syncthreads();
  float mu = red[8], rsg = red[9];
  float4 gv = ((const float4*)g)[tid];
  float4 bv = ((const float4*)b)[tid];
  float4 o;
  o.x = (v.x - mu) * rsg * gv.x + bv.x;
  o.y = (v.y - mu) * rsg * gv.y + bv.y;
  o.z = (v.z - mu) * rsg * gv.z + bv.z;
  o.w = (v.w - mu) * rsg * gv.w + bv.w;
  if (outf) ((float4*)(outf + (size_t)row * D_))[tid] = o;
  if (WB) {
    ushort4 ob;
    ob.x = f2bf(o.x); ob.y = f2bf(o.y); ob.z = f2bf(o.z); ob.w = f2bf(o.w);
    ((ushort4*)(outb + (size_t)row * D_))[tid] = ob;
  }
}

extern "C" void kernel_launch(void* const* d_in, const int* in_sizes, int n_in,
                              void* d_out, int out_size, void* d_ws, size_t ws_size,
                              hipStream_t stream) {
  const float* x   = (const float*)d_in[0];
  const float* Wq  = (const float*)d_in[1];
  const float* bq  = (const float*)d_in[2];
  const float* Wk  = (const float*)d_in[3];
  const float* bk  = (const float*)d_in[4];
  const float* Wv  = (const float*)d_in[5];
  const float* bv  = (const float*)d_in[6];
  const float* Wo  = (const float*)d_in[7];
  const float* bo  = (const float*)d_in[8];
  const float* g1  = (const float*)d_in[9];
  const float* b1  = (const float*)d_in[10];
  const float* W1  = (const float*)d_in[11];
  const float* bm1 = (const float*)d_in[12];
  const float* W2  = (const float*)d_in[13];
  const float* bm2 = (const float*)d_in[14];
  const float* g2  = (const float*)d_in[15];
  const float* b2  = (const float*)d_in[16];
  float* out = (float*)d_out;

  char* ws = (char*)d_ws;
  const size_t MB = 1024 * 1024;
  ushort_t* xb    = (ushort_t*)(ws + 0);         // 8 MB   (dead after QKV gemm)
  ushort_t* wqkvt = (ushort_t*)(ws + 8 * MB);    // 6 MB
  ushort_t* wot   = (ushort_t*)(ws + 14 * MB);   // 2 MB
  ushort_t* w1t   = (ushort_t*)(ws + 16 * MB);   // 8 MB
  ushort_t* w2t   = (ushort_t*)(ws + 24 * MB);   // 8 MB
  ushort_t* qb    = (ushort_t*)(ws + 32 * MB);   // 8 MB   (dead after flash)
  ushort_t* kb    = (ushort_t*)(ws + 40 * MB);   // 8 MB   (dead after flash)
  ushort_t* vtb   = (ushort_t*)(ws + 48 * MB);   // 8 MB   (dead after flash)
  ushort_t* ctx   = (ushort_t*)(ws + 56 * MB);   // 8 MB   (dead after Wo gemm)
  float*    x1    = (float*)   (ws + 64 * MB);   // 16 MB
  ushort_t* x1b   = (ushort_t*)(ws + 80 * MB);   // 8 MB
  ushort_t* hbuf  = (ushort_t*)(ws + 88 * MB);   // 32 MB
  ushort_t* pWo   = (ushort_t*)(ws + 32 * MB);   // 16 MB over qb+kb
  ushort_t* pMd   = (ushort_t*)(ws + 32 * MB);   // 32 MB over qb..ctx
  (void)ws_size; (void)in_sizes; (void)n_in; (void)out_size;

  // 1. fused prep: cast x + all weight transposes
  hipLaunchKernelGGL(prep_kernel, dim3(16384), dim3(256), 0, stream,
                     x, Wq, Wk, Wv, Wo, W1, W2, xb, wqkvt, wot, w1t, w2t);

  // 2. fused QKV projection (M=4096, N=3072, K=1024); V written transposed
  hipLaunchKernelGGL((gemm_bf16<0>), dim3(768), dim3(256), 0, stream,
                     xb, wqkvt, NTOK, 3072, D_, D_, 768, bq, bk, bv, qb, kb, vtb);

  // 3. attention (128-row q tiles)
  hipLaunchKernelGGL(flash_attn_kernel, dim3(4 * HH, SQLEN / 128), dim3(256), 0, stream,
                     qb, kb, vtb, ctx);

  // 4. output projection, split-K=2 -> bf16 partials pWo
  hipLaunchKernelGGL((gemm_bf16<3>), dim3(512), dim3(256), 0, stream,
                     ctx, wot, NTOK, D_, D_, 512, 256,
                     (const float*)nullptr, (const float*)nullptr,
                     (const float*)nullptr, pWo, (ushort_t*)nullptr, (ushort_t*)nullptr);

  // 5. LN1 = LN(x + bo + sum partials) -> x1 (fp32) + x1b (bf16)
  hipLaunchKernelGGL((ln_red_kernel<2, 1>), dim3(NTOK), dim3(256), 0, stream,
                     pWo, bo, x, g1, b1, x1, x1b);

  // 6. MLP up + GELU -> hbuf (M=4096, N=4096, K=1024)
  hipLaunchKernelGGL((gemm_bf16<2>), dim3(1024), dim3(256), 0, stream,
                     x1b, w1t, NTOK, DFF_, D_, D_, 1024, bm1, (const float*)nullptr,
                     (const float*)nullptr, hbuf, (ushort_t*)nullptr, (ushort_t*)nullptr);

  // 7. MLP down, split-K=4 -> bf16 partials pMd
  hipLaunchKernelGGL((gemm_bf16<3>), dim3(1024), dim3(256), 0, stream,
                     hbuf, w2t, NTOK, D_, DFF_, 1024, 256,
                     (const float*)nullptr, (const float*)nullptr,
                     (const float*)nullptr, pMd, (ushort_t*)nullptr, (ushort_t*)nullptr);

  // 8. LN2 = LN(x1 + bm2 + sum partials) -> out
  hipLaunchKernelGGL((ln_red_kernel<4, 0>), dim3(NTOK), dim3(256), 0, stream,
                     pMd, bm2, x1, g2, b2, out, (ushort_t*)nullptr);
}